// Round 8
// baseline (21705.458 us; speedup 1.0000x reference)
//
#include <hip/hip_runtime.h>
#include <math.h>

#define B 8
#define P 2048
#define D 64
#define EPS 0.1f
#define INVEPS 10.0f
#define MAXIT 100
#define THRESH 0.1f
#define NBLK 512                   // persistent grid: 2 blocks/CU guaranteed
#define FSTRIDE 4                  // flag stride in words (16B apart)

#define S2F    14.4269504089f      // 10 * log2(e)  (into exp2 domain)
#define TWOS2F 28.8539008177f      // 2 * S2F
#define EPSLN2 0.069314718056f     // EPS * ln(2)

// exp2/log2: avoid __exp2f/__log2f spellings (collide with glibc math.h
// internal decls). Use AMDGCN builtins (v_exp_f32 / v_log_f32) on device.
#if defined(__AMDGCN__) && __has_builtin(__builtin_amdgcn_exp2f)
#define EXP2F(x) __builtin_amdgcn_exp2f(x)
#else
#define EXP2F(x) exp2f(x)
#endif
#if defined(__AMDGCN__) && __has_builtin(__builtin_amdgcn_logf)
#define LOG2F(x) __builtin_amdgcn_logf(x)
#else
#define LOG2F(x) log2f(x)
#endif

typedef _Float16 f16x8 __attribute__((ext_vector_type(8)));
typedef float    f32x4 __attribute__((ext_vector_type(4)));

// ---------------- C build: C[b,i,j] = sum_d (x[b,i,d]-y[b,j,d])^2 ----------
__global__ __launch_bounds__(256) void build_C(const float* __restrict__ x,
                                               const float* __restrict__ y,
                                               float* __restrict__ C) {
    __shared__ float xs[64 * 68];
    __shared__ float ys[64 * 68];
    const int tid = threadIdx.x;
    const int blk = blockIdx.x;        // 8 * 32 * 32 = 8192 blocks
    const int b   = blk >> 10;
    const int rem = blk & 1023;
    const int i0  = (rem >> 5) << 6;
    const int j0  = (rem & 31) << 6;

    const float4* xg = (const float4*)(x + ((size_t)(b * P + i0)) * D);
    const float4* yg = (const float4*)(y + ((size_t)(b * P + j0)) * D);
#pragma unroll
    for (int p = 0; p < 4; ++p) {
        int q = tid + (p << 8);
        int row = q >> 4, c4 = q & 15;
        float4 xv = xg[row * 16 + c4];
        float4 yv = yg[row * 16 + c4];
        float* xd = &xs[row * 68 + (c4 << 2)];
        xd[0] = xv.x; xd[1] = xv.y; xd[2] = xv.z; xd[3] = xv.w;
        float* yd = &ys[row * 68 + (c4 << 2)];
        yd[0] = yv.x; yd[1] = yv.y; yd[2] = yv.z; yd[3] = yv.w;
    }
    __syncthreads();

    const int ti = tid >> 4, tj = tid & 15;
    float acc[4][4] = {};
#pragma unroll 4
    for (int d4 = 0; d4 < 16; ++d4) {
        float4 xa[4], yb[4];
#pragma unroll
        for (int a = 0; a < 4; ++a)
            xa[a] = *(const float4*)&xs[(ti * 4 + a) * 68 + (d4 << 2)];
#pragma unroll
        for (int bb = 0; bb < 4; ++bb)
            yb[bb] = *(const float4*)&ys[(tj * 4 + bb) * 68 + (d4 << 2)];
#pragma unroll
        for (int a = 0; a < 4; ++a)
#pragma unroll
            for (int bb = 0; bb < 4; ++bb) {
                float dx = xa[a].x - yb[bb].x;
                float dy = xa[a].y - yb[bb].y;
                float dz = xa[a].z - yb[bb].z;
                float dw = xa[a].w - yb[bb].w;
                acc[a][bb] += dx * dx + dy * dy + dz * dz + dw * dw;
            }
    }
    size_t base = ((size_t)b * P + (i0 + ti * 4)) * P + (j0 + tj * 4);
#pragma unroll
    for (int a = 0; a < 4; ++a) {
        float4 o = make_float4(acc[a][0], acc[a][1], acc[a][2], acc[a][3]);
        *(float4*)&C[base + (size_t)a * P] = o;
    }
}

// -------- online logsumexp helpers (exp2 domain: m=max(z2), s=sum 2^(z2-m)) ----
__device__ __forceinline__ void lse_push2(float z, float& m, float& s) {
    float d = z - m;
    float w = EXP2F(-fabsf(d));       // 2^(min-max); first push: d=+inf -> w=0
    bool gt = d > 0.0f;
    m = gt ? z : m;
    s = fmaf(s, gt ? w : 1.0f, gt ? 1.0f : w);
}
__device__ __forceinline__ void lse_merge2(float mo, float so, float& m, float& s) {
    float M = fmaxf(m, mo);
    s = s * EXP2F(m - M) + so * EXP2F(mo - M);
    m = M;
}

// ---- setup: fp16 copies of x,y + squared norms + initial w2 = -yn*S2F -----
__global__ __launch_bounds__(256) void setup_half(
        const float* __restrict__ x, const float* __restrict__ y,
        _Float16* __restrict__ xh, _Float16* __restrict__ yh,
        float* __restrict__ xn, float* __restrict__ yn,
        float* __restrict__ w2g) {
    const int tid = threadIdx.x;
    const int pt  = blockIdx.x * 32 + (tid >> 3);   // 0..B*P-1
    const int l8  = tid & 7;
    const size_t off = (size_t)pt * D + l8 * 8;
    float4 a0 = *(const float4*)(x + off);
    float4 a1 = *(const float4*)(x + off + 4);
    f16x8 hx;
    hx[0]=(_Float16)a0.x; hx[1]=(_Float16)a0.y; hx[2]=(_Float16)a0.z; hx[3]=(_Float16)a0.w;
    hx[4]=(_Float16)a1.x; hx[5]=(_Float16)a1.y; hx[6]=(_Float16)a1.z; hx[7]=(_Float16)a1.w;
    *(f16x8*)(xh + off) = hx;
    float nx = a0.x*a0.x + a0.y*a0.y + a0.z*a0.z + a0.w*a0.w
             + a1.x*a1.x + a1.y*a1.y + a1.z*a1.z + a1.w*a1.w;
    float4 b0 = *(const float4*)(y + off);
    float4 b1 = *(const float4*)(y + off + 4);
    f16x8 hy;
    hy[0]=(_Float16)b0.x; hy[1]=(_Float16)b0.y; hy[2]=(_Float16)b0.z; hy[3]=(_Float16)b0.w;
    hy[4]=(_Float16)b1.x; hy[5]=(_Float16)b1.y; hy[6]=(_Float16)b1.z; hy[7]=(_Float16)b1.w;
    *(f16x8*)(yh + off) = hy;
    float ny = b0.x*b0.x + b0.y*b0.y + b0.z*b0.z + b0.w*b0.w
             + b1.x*b1.x + b1.y*b1.y + b1.z*b1.z + b1.w*b1.w;
#pragma unroll
    for (int o = 1; o < 8; o <<= 1) {
        nx += __shfl_xor(nx, o, 8);
        ny += __shfl_xor(ny, o, 8);
    }
    if (l8 == 0) { xn[pt] = nx; yn[pt] = ny; w2g[pt] = -ny * S2F; }
}

// ---------------- init: zero u, v, err accumulators, barrier state, cost ---
__global__ void init_ws(float* __restrict__ u, float* __restrict__ v,
                        float* __restrict__ errAcc, unsigned* __restrict__ gen,
                        unsigned* __restrict__ flags, float* __restrict__ cost) {
    int idx = blockIdx.x * blockDim.x + threadIdx.x;
    if (idx < B * P) { u[idx] = 0.0f; v[idx] = 0.0f; }
    if (idx < MAXIT) errAcc[idx] = 0.0f;
    if (idx == 0) *gen = 0u;
    if (idx < NBLK * FSTRIDE) flags[idx] = 0u;
    if (idx < B) cost[idx] = 0.0f;
}

// ---- grid barrier, contention-free: per-block flag stores (no RMW) +
// master sweep + gen broadcast. All NBLK blocks co-resident by LB. ---------
__device__ __forceinline__ void gridbar(unsigned* __restrict__ flags,
                                        unsigned* __restrict__ gen,
                                        unsigned tgt) {
    __syncthreads();
    if (threadIdx.x == 0) {
        __threadfence();   // release this block's writes to device scope
        __hip_atomic_store(&flags[blockIdx.x * FSTRIDE], tgt,
                           __ATOMIC_RELEASE, __HIP_MEMORY_SCOPE_AGENT);
    }
    if (blockIdx.x == 0) {
        // master: 512 threads sweep one flag each (parallel, read-only spin)
        for (int i = threadIdx.x; i < NBLK; i += 512)
            while (__hip_atomic_load(&flags[i * FSTRIDE], __ATOMIC_ACQUIRE,
                                     __HIP_MEMORY_SCOPE_AGENT) < tgt)
                __builtin_amdgcn_s_sleep(1);
        __syncthreads();
        if (threadIdx.x == 0)
            __hip_atomic_store(gen, tgt, __ATOMIC_RELEASE,
                               __HIP_MEMORY_SCOPE_AGENT);
    } else if (threadIdx.x == 0) {
        while (__hip_atomic_load(gen, __ATOMIC_ACQUIRE,
                                 __HIP_MEMORY_SCOPE_AGENT) < tgt)
            __builtin_amdgcn_s_sleep(1);
    }
    if (threadIdx.x == 0) __threadfence();   // acquire: invalidate stale caches
    __syncthreads();
}

// ---- persistent iteration kernel: all MAXIT iterations in ONE launch ------
// 512 blocks x 512 thr (8 waves, 2 blocks/CU -> 16 waves/CU). Block blk:
// b = blk>>6, q = blk&63, rows r0..r0+31. Wave wid streams cols wid*256 +
// ct*16 (16 ct-tiles); G via fp16 MFMA; row-LSE -> u, a2. Phase B mirrors
// with x<->y swapped (full column LSE -> v, w2). No merge kernel.
__global__ __launch_bounds__(512, 4) void iter_persist(
        const _Float16* __restrict__ xh, const _Float16* __restrict__ yh,
        const float* __restrict__ xn, const float* __restrict__ yn,
        float* __restrict__ a2g, float* __restrict__ w2g,
        float* __restrict__ u, float* __restrict__ vg,
        float* __restrict__ errAcc, unsigned* __restrict__ flags,
        unsigned* __restrict__ gen) {
    __shared__ float  sw[P];           // staged w2 (phase A) / a2 (phase B)
    __shared__ float2 wavepart[8][32];
    const int tid = threadIdx.x, lane = tid & 63, wid = tid >> 6;  // 8 waves
    const int lg = lane >> 4, li = lane & 15;
    const int b = blockIdx.x >> 6, q = blockIdx.x & 63;
    const int r0 = q * 32;
    const float eps_logmu = EPS * logf(1.0f / (float)P + 1e-8f);

    // persistent MFMA A-operand fragments: x rows r0.. (A), y rows r0.. (B)
    f16x8 Af[2][2], Bf[2][2];
#pragma unroll
    for (int mt = 0; mt < 2; ++mt)
#pragma unroll
        for (int kc = 0; kc < 2; ++kc) {
            size_t o = ((size_t)(b * P + r0 + mt * 16 + li)) * D + kc * 32 + lg * 8;
            Af[mt][kc] = *(const f16x8*)(xh + o);
            Bf[mt][kc] = *(const f16x8*)(yh + o);
        }
    float xnr = 0.0f, ynr = 0.0f;
    if (tid < 32) { xnr = xn[b * P + r0 + tid]; ynr = yn[b * P + r0 + tid]; }

    const _Float16* ybase = yh + ((size_t)(b * P + wid * 256 + li)) * D + lg * 8;
    const _Float16* xbase = xh + ((size_t)(b * P + wid * 256 + li)) * D + lg * 8;

    unsigned tgt = 0;
    for (int t = 0; t < MAXIT; ++t) {
        // ================= phase A: u update =================
        ((float4*)sw)[tid] = ((const float4*)(w2g + (size_t)b * P))[tid];
        __syncthreads();
        {
            float rm[8], rs[8];
#pragma unroll
            for (int c = 0; c < 8; ++c) { rm[c] = -INFINITY; rs[c] = 0.0f; }
            f16x8 Xb0[2], Xb1[2];
            Xb0[0] = *(const f16x8*)(ybase);
            Xb1[0] = *(const f16x8*)(ybase + 32);
#pragma unroll
            for (int ct = 0; ct < 16; ++ct) {
                const int cur = ct & 1, nx = cur ^ 1;
                if (ct < 15) {
                    Xb0[nx] = *(const f16x8*)(ybase + (size_t)(ct + 1) * 16 * D);
                    Xb1[nx] = *(const f16x8*)(ybase + (size_t)(ct + 1) * 16 * D + 32);
                }
                f32x4 g0 = {0.f, 0.f, 0.f, 0.f}, g1 = {0.f, 0.f, 0.f, 0.f};
                g0 = __builtin_amdgcn_mfma_f32_16x16x32_f16(Af[0][0], Xb0[cur], g0, 0, 0, 0);
                g0 = __builtin_amdgcn_mfma_f32_16x16x32_f16(Af[0][1], Xb1[cur], g0, 0, 0, 0);
                g1 = __builtin_amdgcn_mfma_f32_16x16x32_f16(Af[1][0], Xb0[cur], g1, 0, 0, 0);
                g1 = __builtin_amdgcn_mfma_f32_16x16x32_f16(Af[1][1], Xb1[cur], g1, 0, 0, 0);
                float w2c = sw[(wid << 8) + (ct << 4) + li];
#pragma unroll
                for (int reg = 0; reg < 4; ++reg) {
                    lse_push2(fmaf(g0[reg], TWOS2F, w2c), rm[reg],     rs[reg]);
                    lse_push2(fmaf(g1[reg], TWOS2F, w2c), rm[4 + reg], rs[4 + reg]);
                }
            }
#pragma unroll
            for (int off = 1; off < 16; off <<= 1)
#pragma unroll
                for (int c = 0; c < 8; ++c) {
                    float mo = __shfl_xor(rm[c], off, 64);
                    float so = __shfl_xor(rs[c], off, 64);
                    lse_merge2(mo, so, rm[c], rs[c]);
                }
            if (li == 0) {
#pragma unroll
                for (int c = 0; c < 8; ++c)
                    wavepart[wid][((c >> 2) << 4) + (lg << 2) + (c & 3)] =
                        make_float2(rm[c], rs[c]);
            }
        }
        __syncthreads();
        if (tid < 32) {
            float m = wavepart[0][tid].x, s = wavepart[0][tid].y;
#pragma unroll
            for (int w = 1; w < 8; ++w)
                lse_merge2(wavepart[w][tid].x, wavepart[w][tid].y, m, s);
            float unew = eps_logmu + xnr - EPSLN2 * (m + LOG2F(s));
            int gi = b * P + r0 + tid;
            float e = fabsf(unew - u[gi]);
            u[gi] = unew;
            a2g[gi] = (unew - xnr) * S2F;
#pragma unroll
            for (int off = 16; off; off >>= 1) e += __shfl_xor(e, off, 32);
            if (tid == 0) atomicAdd(&errAcc[t], e);
        }
        gridbar(flags, gen, ++tgt);

        // ================= phase B: v update (mirror) =================
        ((float4*)sw)[tid] = ((const float4*)(a2g + (size_t)b * P))[tid];
        __syncthreads();
        {
            float rm[8], rs[8];
#pragma unroll
            for (int c = 0; c < 8; ++c) { rm[c] = -INFINITY; rs[c] = 0.0f; }
            f16x8 Xb0[2], Xb1[2];
            Xb0[0] = *(const f16x8*)(xbase);
            Xb1[0] = *(const f16x8*)(xbase + 32);
#pragma unroll
            for (int ct = 0; ct < 16; ++ct) {
                const int cur = ct & 1, nx = cur ^ 1;
                if (ct < 15) {
                    Xb0[nx] = *(const f16x8*)(xbase + (size_t)(ct + 1) * 16 * D);
                    Xb1[nx] = *(const f16x8*)(xbase + (size_t)(ct + 1) * 16 * D + 32);
                }
                f32x4 g0 = {0.f, 0.f, 0.f, 0.f}, g1 = {0.f, 0.f, 0.f, 0.f};
                g0 = __builtin_amdgcn_mfma_f32_16x16x32_f16(Bf[0][0], Xb0[cur], g0, 0, 0, 0);
                g0 = __builtin_amdgcn_mfma_f32_16x16x32_f16(Bf[0][1], Xb1[cur], g0, 0, 0, 0);
                g1 = __builtin_amdgcn_mfma_f32_16x16x32_f16(Bf[1][0], Xb0[cur], g1, 0, 0, 0);
                g1 = __builtin_amdgcn_mfma_f32_16x16x32_f16(Bf[1][1], Xb1[cur], g1, 0, 0, 0);
                float a2i = sw[(wid << 8) + (ct << 4) + li];
#pragma unroll
                for (int reg = 0; reg < 4; ++reg) {
                    lse_push2(fmaf(g0[reg], TWOS2F, a2i), rm[reg],     rs[reg]);
                    lse_push2(fmaf(g1[reg], TWOS2F, a2i), rm[4 + reg], rs[4 + reg]);
                }
            }
#pragma unroll
            for (int off = 1; off < 16; off <<= 1)
#pragma unroll
                for (int c = 0; c < 8; ++c) {
                    float mo = __shfl_xor(rm[c], off, 64);
                    float so = __shfl_xor(rs[c], off, 64);
                    lse_merge2(mo, so, rm[c], rs[c]);
                }
            if (li == 0) {
#pragma unroll
                for (int c = 0; c < 8; ++c)
                    wavepart[wid][((c >> 2) << 4) + (lg << 2) + (c & 3)] =
                        make_float2(rm[c], rs[c]);
            }
        }
        __syncthreads();
        if (tid < 32) {
            float m = wavepart[0][tid].x, s = wavepart[0][tid].y;
#pragma unroll
            for (int w = 1; w < 8; ++w)
                lse_merge2(wavepart[w][tid].x, wavepart[w][tid].y, m, s);
            float vnew = eps_logmu + ynr - EPSLN2 * (m + LOG2F(s));
            int gj = b * P + r0 + tid;
            vg[gj] = vnew;
            w2g[gj] = (vnew - ynr) * S2F;
        }
        gridbar(flags, gen, ++tgt);

        // uniform convergence check (same completed value in every block)
        if (__hip_atomic_load(&errAcc[t], __ATOMIC_RELAXED,
                              __HIP_MEMORY_SCOPE_AGENT) < THRESH * (float)B)
            break;
    }
}

// ---- final: pi = exp((u+v-C)/eps), cost[b] = sum pi*C ---------------------
__global__ __launch_bounds__(256) void final_pi_cost(
        const float* __restrict__ C, const float* __restrict__ u,
        const float* __restrict__ vg, float* __restrict__ pi,
        float* __restrict__ cost) {
    __shared__ float sc[B];
    const int tid = threadIdx.x, lane = tid & 63, wid = tid >> 6;
    if (tid < B) sc[tid] = 0.0f;
    __syncthreads();
    const int gw = blockIdx.x * 4 + wid;      // 0..4095
    const int rbase = gw * 4;
    if (rbase >= B * P) return;               // defensive
    const int b = rbase >> 11;
    const float4* vrow = (const float4*)(vg + b * P);
    float acc = 0.0f;
    for (int k = 0; k < 4; ++k) {
        const int r = rbase + k;
        const float ur = u[r];
        const float4* Crow = (const float4*)(C + (size_t)r * P);
        float4* prow = (float4*)(pi + (size_t)r * P);
        for (int it = lane; it < P / 4; it += 64) {
            float4 c4 = Crow[it];
            float4 v4 = vrow[it];
            float4 p4;
            p4.x = __expf((ur + v4.x - c4.x) * INVEPS);
            p4.y = __expf((ur + v4.y - c4.y) * INVEPS);
            p4.z = __expf((ur + v4.z - c4.z) * INVEPS);
            p4.w = __expf((ur + v4.w - c4.w) * INVEPS);
            prow[it] = p4;
            acc += p4.x * c4.x + p4.y * c4.y + p4.z * c4.z + p4.w * c4.w;
        }
    }
#pragma unroll
    for (int off = 32; off; off >>= 1) acc += __shfl_xor(acc, off, 64);
    if (lane == 0) atomicAdd(&sc[b], acc);
    __syncthreads();
    if (tid < B && sc[tid] != 0.0f) atomicAdd(&cost[tid], sc[tid]);
}

extern "C" void kernel_launch(void* const* d_in, const int* in_sizes, int n_in,
                              void* d_out, int out_size, void* d_ws, size_t ws_size,
                              hipStream_t stream) {
    const float* x = (const float*)d_in[0];
    const float* y = (const float*)d_in[1];
    float* out  = (float*)d_out;
    float* cost = out;                              // [8]
    float* pi   = out + 8;                          // [8*2048*2048]
    float* C    = out + 8 + (size_t)B * P * P;      // [8*2048*2048]

    // Scratch lives in the pi output region (dead until final_pi_cost
    // overwrites the whole region):
    _Float16* xh  = (_Float16*)pi;                  // 2 MB (524288 floats)
    _Float16* yh  = (_Float16*)(pi + 524288);       // 2 MB
    float*    xnb = pi + 1048576;                   // B*P
    float*    ynb = xnb + B * P;
    float*    w2g = ynb + B * P;
    float*    a2g = w2g + B * P;

    float* ws       = (float*)d_ws;
    float* u        = ws;                           // B*P
    float* v        = ws + B * P;                   // B*P
    float* errAcc   = ws + 2 * B * P;               // MAXIT
    unsigned* gen   = (unsigned*)(ws + 2 * B * P + 128);   // [1]
    unsigned* flags = gen + 64;                     // NBLK*FSTRIDE words (8 KB)

    hipLaunchKernelGGL(build_C, dim3(8 * 32 * 32), dim3(256), 0, stream, x, y, C);
    hipLaunchKernelGGL(setup_half, dim3(B * P / 32), dim3(256), 0, stream,
                       x, y, xh, yh, xnb, ynb, w2g);
    hipLaunchKernelGGL(init_ws, dim3(64), dim3(256), 0, stream,
                       u, v, errAcc, gen, flags, cost);

    hipLaunchKernelGGL(iter_persist, dim3(NBLK), dim3(512), 0, stream,
                       (const _Float16*)xh, (const _Float16*)yh,
                       (const float*)xnb, (const float*)ynb,
                       a2g, w2g, u, v, errAcc, flags, gen);

    hipLaunchKernelGGL(final_pi_cost, dim3(1024), dim3(256), 0, stream,
                       (const float*)C, (const float*)u, (const float*)v,
                       pi, cost);
}

// Round 9
// 6415.932 us; speedup vs baseline: 3.3831x; 3.3831x over previous
//
#include <hip/hip_runtime.h>
#include <math.h>

#define B 8
#define P 2048
#define D 64
#define EPS 0.1f
#define INVEPS 10.0f
#define MAXIT 100
#define THRESH 0.1f
#define NBLK 512                   // persistent grid: 2 blocks/CU guaranteed
#define DONEBIT 0x80000000u

#define S2F    14.4269504089f      // 10 * log2(e)  (into exp2 domain)
#define TWOS2F 28.8539008177f      // 2 * S2F
#define EPSLN2 0.069314718056f     // EPS * ln(2)

// exp2/log2: avoid __exp2f/__log2f spellings (collide with glibc math.h
// internal decls). Use AMDGCN builtins (v_exp_f32 / v_log_f32) on device.
#if defined(__AMDGCN__) && __has_builtin(__builtin_amdgcn_exp2f)
#define EXP2F(x) __builtin_amdgcn_exp2f(x)
#else
#define EXP2F(x) exp2f(x)
#endif
#if defined(__AMDGCN__) && __has_builtin(__builtin_amdgcn_logf)
#define LOG2F(x) __builtin_amdgcn_logf(x)
#else
#define LOG2F(x) log2f(x)
#endif

typedef _Float16 f16x8 __attribute__((ext_vector_type(8)));
typedef float    f32x4 __attribute__((ext_vector_type(4)));

// coherent (LLC) scalar accessors — relaxed, agent scope: plain sc1 ops,
// NO buffer_inv / NO wbl2 (never invalidates L2; cache stays warm).
__device__ __forceinline__ float ld_coh(const float* p) {
    unsigned r = __hip_atomic_load((const unsigned*)p, __ATOMIC_RELAXED,
                                   __HIP_MEMORY_SCOPE_AGENT);
    return __uint_as_float(r);
}
__device__ __forceinline__ void st_coh(float* p, float v) {
    __hip_atomic_store((unsigned*)p, __float_as_uint(v), __ATOMIC_RELAXED,
                       __HIP_MEMORY_SCOPE_AGENT);
}

// ---------------- C build: C[b,i,j] = sum_d (x[b,i,d]-y[b,j,d])^2 ----------
__global__ __launch_bounds__(256) void build_C(const float* __restrict__ x,
                                               const float* __restrict__ y,
                                               float* __restrict__ C) {
    __shared__ float xs[64 * 68];
    __shared__ float ys[64 * 68];
    const int tid = threadIdx.x;
    const int blk = blockIdx.x;        // 8 * 32 * 32 = 8192 blocks
    const int b   = blk >> 10;
    const int rem = blk & 1023;
    const int i0  = (rem >> 5) << 6;
    const int j0  = (rem & 31) << 6;

    const float4* xg = (const float4*)(x + ((size_t)(b * P + i0)) * D);
    const float4* yg = (const float4*)(y + ((size_t)(b * P + j0)) * D);
#pragma unroll
    for (int p = 0; p < 4; ++p) {
        int q = tid + (p << 8);
        int row = q >> 4, c4 = q & 15;
        float4 xv = xg[row * 16 + c4];
        float4 yv = yg[row * 16 + c4];
        float* xd = &xs[row * 68 + (c4 << 2)];
        xd[0] = xv.x; xd[1] = xv.y; xd[2] = xv.z; xd[3] = xv.w;
        float* yd = &ys[row * 68 + (c4 << 2)];
        yd[0] = yv.x; yd[1] = yv.y; yd[2] = yv.z; yd[3] = yv.w;
    }
    __syncthreads();

    const int ti = tid >> 4, tj = tid & 15;
    float acc[4][4] = {};
#pragma unroll 4
    for (int d4 = 0; d4 < 16; ++d4) {
        float4 xa[4], yb[4];
#pragma unroll
        for (int a = 0; a < 4; ++a)
            xa[a] = *(const float4*)&xs[(ti * 4 + a) * 68 + (d4 << 2)];
#pragma unroll
        for (int bb = 0; bb < 4; ++bb)
            yb[bb] = *(const float4*)&ys[(tj * 4 + bb) * 68 + (d4 << 2)];
#pragma unroll
        for (int a = 0; a < 4; ++a)
#pragma unroll
            for (int bb = 0; bb < 4; ++bb) {
                float dx = xa[a].x - yb[bb].x;
                float dy = xa[a].y - yb[bb].y;
                float dz = xa[a].z - yb[bb].z;
                float dw = xa[a].w - yb[bb].w;
                acc[a][bb] += dx * dx + dy * dy + dz * dz + dw * dw;
            }
    }
    size_t base = ((size_t)b * P + (i0 + ti * 4)) * P + (j0 + tj * 4);
#pragma unroll
    for (int a = 0; a < 4; ++a) {
        float4 o = make_float4(acc[a][0], acc[a][1], acc[a][2], acc[a][3]);
        *(float4*)&C[base + (size_t)a * P] = o;
    }
}

// -------- online logsumexp helpers (exp2 domain: m=max(z2), s=sum 2^(z2-m)) ----
__device__ __forceinline__ void lse_push2(float z, float& m, float& s) {
    float d = z - m;
    float w = EXP2F(-fabsf(d));       // 2^(min-max); first push: d=+inf -> w=0
    bool gt = d > 0.0f;
    m = gt ? z : m;
    s = fmaf(s, gt ? w : 1.0f, gt ? 1.0f : w);
}
__device__ __forceinline__ void lse_merge2(float mo, float so, float& m, float& s) {
    float M = fmaxf(m, mo);
    s = s * EXP2F(m - M) + so * EXP2F(mo - M);
    m = M;
}

// ---- setup: fp16 copies of x,y + squared norms + initial w2 = -yn*S2F -----
__global__ __launch_bounds__(256) void setup_half(
        const float* __restrict__ x, const float* __restrict__ y,
        _Float16* __restrict__ xh, _Float16* __restrict__ yh,
        float* __restrict__ xn, float* __restrict__ yn,
        float* __restrict__ w2g) {
    const int tid = threadIdx.x;
    const int pt  = blockIdx.x * 32 + (tid >> 3);   // 0..B*P-1
    const int l8  = tid & 7;
    const size_t off = (size_t)pt * D + l8 * 8;
    float4 a0 = *(const float4*)(x + off);
    float4 a1 = *(const float4*)(x + off + 4);
    f16x8 hx;
    hx[0]=(_Float16)a0.x; hx[1]=(_Float16)a0.y; hx[2]=(_Float16)a0.z; hx[3]=(_Float16)a0.w;
    hx[4]=(_Float16)a1.x; hx[5]=(_Float16)a1.y; hx[6]=(_Float16)a1.z; hx[7]=(_Float16)a1.w;
    *(f16x8*)(xh + off) = hx;
    float nx = a0.x*a0.x + a0.y*a0.y + a0.z*a0.z + a0.w*a0.w
             + a1.x*a1.x + a1.y*a1.y + a1.z*a1.z + a1.w*a1.w;
    float4 b0 = *(const float4*)(y + off);
    float4 b1 = *(const float4*)(y + off + 4);
    f16x8 hy;
    hy[0]=(_Float16)b0.x; hy[1]=(_Float16)b0.y; hy[2]=(_Float16)b0.z; hy[3]=(_Float16)b0.w;
    hy[4]=(_Float16)b1.x; hy[5]=(_Float16)b1.y; hy[6]=(_Float16)b1.z; hy[7]=(_Float16)b1.w;
    *(f16x8*)(yh + off) = hy;
    float ny = b0.x*b0.x + b0.y*b0.y + b0.z*b0.z + b0.w*b0.w
             + b1.x*b1.x + b1.y*b1.y + b1.z*b1.z + b1.w*b1.w;
#pragma unroll
    for (int o = 1; o < 8; o <<= 1) {
        nx += __shfl_xor(nx, o, 8);
        ny += __shfl_xor(ny, o, 8);
    }
    if (l8 == 0) { xn[pt] = nx; yn[pt] = ny; w2g[pt] = -ny * S2F; }
}

// ---------------- init: zero u, v, err accumulators, barrier state, cost ---
__global__ void init_ws(float* __restrict__ u, float* __restrict__ v,
                        float* __restrict__ errAcc, unsigned* __restrict__ gen,
                        unsigned* __restrict__ flags, float* __restrict__ cost) {
    int idx = blockIdx.x * blockDim.x + threadIdx.x;
    if (idx < B * P) { u[idx] = 0.0f; v[idx] = 0.0f; }
    if (idx < MAXIT) errAcc[idx] = 0.0f;
    if (idx == 0) *gen = 0u;
    if (idx < NBLK) flags[idx] = 0u;
    if (idx < B) cost[idx] = 0.0f;
}

// ---- grid barrier: RELAXED polls only (no buffer_inv — L2 stays warm).
// Arrival: release flag store (vmcnt-waits prior sc1 data stores -> LLC).
// Master (block 0): 512 threads sweep one flag each with relaxed sc1 loads,
// then one release store of gen (optionally tagged with DONEBIT from errp).
// Others: thread0 relaxed-polls gen with s_sleep backoff. Transitivity is
// via the LLC serialization point; the trailing asm is a compiler-only
// fence keeping later sc1 loads from hoisting above the spin.
__device__ __forceinline__ unsigned gridbar(unsigned* __restrict__ flags,
                                            unsigned* __restrict__ gen,
                                            unsigned tgt, const float* errp) {
    __shared__ unsigned sgen;
    __syncthreads();
    if (threadIdx.x == 0)
        __hip_atomic_store(&flags[blockIdx.x], tgt, __ATOMIC_RELEASE,
                           __HIP_MEMORY_SCOPE_AGENT);
    if (blockIdx.x == 0) {
        for (int i = threadIdx.x; i < NBLK; i += 512)
            while (__hip_atomic_load(&flags[i], __ATOMIC_RELAXED,
                                     __HIP_MEMORY_SCOPE_AGENT) < tgt)
                __builtin_amdgcn_s_sleep(8);
        __syncthreads();
        if (threadIdx.x == 0) {
            unsigned val = tgt;
            if (errp && ld_coh(errp) < THRESH * (float)B) val |= DONEBIT;
            __hip_atomic_store(gen, val, __ATOMIC_RELEASE,
                               __HIP_MEMORY_SCOPE_AGENT);
            sgen = val;
        }
    } else if (threadIdx.x == 0) {
        unsigned v;
        for (;;) {
            v = __hip_atomic_load(gen, __ATOMIC_RELAXED,
                                  __HIP_MEMORY_SCOPE_AGENT);
            if ((v & ~DONEBIT) >= tgt) break;
            __builtin_amdgcn_s_sleep(8);
        }
        sgen = v;
    }
    __syncthreads();
    unsigned g = sgen;
    asm volatile("" ::: "memory");     // compiler fence only (0 instructions)
    return g;
}

// ---- persistent iteration kernel: all MAXIT iterations in ONE launch ------
// 512 blocks x 512 thr (8 waves, 2 blocks/CU). Block blk: b = blk>>6,
// q = blk&63, rows r0..r0+31. Wave wid streams cols wid*256 + ct*16;
// G via fp16 MFMA; row-LSE -> u, a2. Phase B mirrors with x<->y swapped.
// Cross-block arrays (w2g/a2g) are accessed ONLY via sc1 relaxed atomics;
// xh/yh/u/vg are regular (block-private or read-only) and stay L2-hot.
__global__ __launch_bounds__(512, 4) void iter_persist(
        const _Float16* __restrict__ xh, const _Float16* __restrict__ yh,
        const float* __restrict__ xn, const float* __restrict__ yn,
        float* __restrict__ a2g, float* __restrict__ w2g,
        float* __restrict__ u, float* __restrict__ vg,
        float* __restrict__ errAcc, unsigned* __restrict__ flags,
        unsigned* __restrict__ gen) {
    __shared__ float  sw[P];           // staged w2 (phase A) / a2 (phase B)
    __shared__ float2 wavepart[8][32];
    const int tid = threadIdx.x, lane = tid & 63, wid = tid >> 6;  // 8 waves
    const int lg = lane >> 4, li = lane & 15;
    const int b = blockIdx.x >> 6, q = blockIdx.x & 63;
    const int r0 = q * 32;
    const float eps_logmu = EPS * logf(1.0f / (float)P + 1e-8f);

    // persistent MFMA A-operand fragments: x rows r0.. (A), y rows r0.. (B)
    f16x8 Af[2][2], Bf[2][2];
#pragma unroll
    for (int mt = 0; mt < 2; ++mt)
#pragma unroll
        for (int kc = 0; kc < 2; ++kc) {
            size_t o = ((size_t)(b * P + r0 + mt * 16 + li)) * D + kc * 32 + lg * 8;
            Af[mt][kc] = *(const f16x8*)(xh + o);
            Bf[mt][kc] = *(const f16x8*)(yh + o);
        }
    float xnr = 0.0f, ynr = 0.0f;
    if (tid < 32) { xnr = xn[b * P + r0 + tid]; ynr = yn[b * P + r0 + tid]; }

    const _Float16* ybase = yh + ((size_t)(b * P + wid * 256 + li)) * D + lg * 8;
    const _Float16* xbase = xh + ((size_t)(b * P + wid * 256 + li)) * D + lg * 8;

    for (int t = 0; t < MAXIT; ++t) {
        // ================= phase A: u update =================
#pragma unroll
        for (int k = 0; k < 4; ++k) {     // coherent staging, coalesced
            int idx = tid + (k << 9);
            sw[idx] = ld_coh(&w2g[(size_t)b * P + idx]);
        }
        __syncthreads();
        {
            float rm[8], rs[8];
#pragma unroll
            for (int c = 0; c < 8; ++c) { rm[c] = -INFINITY; rs[c] = 0.0f; }
            f16x8 Xb0[2], Xb1[2];
            Xb0[0] = *(const f16x8*)(ybase);
            Xb1[0] = *(const f16x8*)(ybase + 32);
#pragma unroll
            for (int ct = 0; ct < 16; ++ct) {
                const int cur = ct & 1, nx = cur ^ 1;
                if (ct < 15) {
                    Xb0[nx] = *(const f16x8*)(ybase + (size_t)(ct + 1) * 16 * D);
                    Xb1[nx] = *(const f16x8*)(ybase + (size_t)(ct + 1) * 16 * D + 32);
                }
                f32x4 g0 = {0.f, 0.f, 0.f, 0.f}, g1 = {0.f, 0.f, 0.f, 0.f};
                g0 = __builtin_amdgcn_mfma_f32_16x16x32_f16(Af[0][0], Xb0[cur], g0, 0, 0, 0);
                g0 = __builtin_amdgcn_mfma_f32_16x16x32_f16(Af[0][1], Xb1[cur], g0, 0, 0, 0);
                g1 = __builtin_amdgcn_mfma_f32_16x16x32_f16(Af[1][0], Xb0[cur], g1, 0, 0, 0);
                g1 = __builtin_amdgcn_mfma_f32_16x16x32_f16(Af[1][1], Xb1[cur], g1, 0, 0, 0);
                float w2c = sw[(wid << 8) + (ct << 4) + li];
#pragma unroll
                for (int reg = 0; reg < 4; ++reg) {
                    lse_push2(fmaf(g0[reg], TWOS2F, w2c), rm[reg],     rs[reg]);
                    lse_push2(fmaf(g1[reg], TWOS2F, w2c), rm[4 + reg], rs[4 + reg]);
                }
            }
#pragma unroll
            for (int off = 1; off < 16; off <<= 1)
#pragma unroll
                for (int c = 0; c < 8; ++c) {
                    float mo = __shfl_xor(rm[c], off, 64);
                    float so = __shfl_xor(rs[c], off, 64);
                    lse_merge2(mo, so, rm[c], rs[c]);
                }
            if (li == 0) {
#pragma unroll
                for (int c = 0; c < 8; ++c)
                    wavepart[wid][((c >> 2) << 4) + (lg << 2) + (c & 3)] =
                        make_float2(rm[c], rs[c]);
            }
        }
        __syncthreads();
        if (tid < 32) {
            float m = wavepart[0][tid].x, s = wavepart[0][tid].y;
#pragma unroll
            for (int w = 1; w < 8; ++w)
                lse_merge2(wavepart[w][tid].x, wavepart[w][tid].y, m, s);
            float unew = eps_logmu + xnr - EPSLN2 * (m + LOG2F(s));
            int gi = b * P + r0 + tid;
            float e = fabsf(unew - u[gi]);
            u[gi] = unew;                         // block-private (regular)
            st_coh(&a2g[gi], (unew - xnr) * S2F); // cross-block (coherent)
#pragma unroll
            for (int off = 16; off; off >>= 1) e += __shfl_xor(e, off, 32);
            if (tid == 0) atomicAdd(&errAcc[t], e);
        }
        gridbar(flags, gen, 2 * t + 1, nullptr);

        // ================= phase B: v update (mirror) =================
#pragma unroll
        for (int k = 0; k < 4; ++k) {
            int idx = tid + (k << 9);
            sw[idx] = ld_coh(&a2g[(size_t)b * P + idx]);
        }
        __syncthreads();
        {
            float rm[8], rs[8];
#pragma unroll
            for (int c = 0; c < 8; ++c) { rm[c] = -INFINITY; rs[c] = 0.0f; }
            f16x8 Xb0[2], Xb1[2];
            Xb0[0] = *(const f16x8*)(xbase);
            Xb1[0] = *(const f16x8*)(xbase + 32);
#pragma unroll
            for (int ct = 0; ct < 16; ++ct) {
                const int cur = ct & 1, nx = cur ^ 1;
                if (ct < 15) {
                    Xb0[nx] = *(const f16x8*)(xbase + (size_t)(ct + 1) * 16 * D);
                    Xb1[nx] = *(const f16x8*)(xbase + (size_t)(ct + 1) * 16 * D + 32);
                }
                f32x4 g0 = {0.f, 0.f, 0.f, 0.f}, g1 = {0.f, 0.f, 0.f, 0.f};
                g0 = __builtin_amdgcn_mfma_f32_16x16x32_f16(Bf[0][0], Xb0[cur], g0, 0, 0, 0);
                g0 = __builtin_amdgcn_mfma_f32_16x16x32_f16(Bf[0][1], Xb1[cur], g0, 0, 0, 0);
                g1 = __builtin_amdgcn_mfma_f32_16x16x32_f16(Bf[1][0], Xb0[cur], g1, 0, 0, 0);
                g1 = __builtin_amdgcn_mfma_f32_16x16x32_f16(Bf[1][1], Xb1[cur], g1, 0, 0, 0);
                float a2i = sw[(wid << 8) + (ct << 4) + li];
#pragma unroll
                for (int reg = 0; reg < 4; ++reg) {
                    lse_push2(fmaf(g0[reg], TWOS2F, a2i), rm[reg],     rs[reg]);
                    lse_push2(fmaf(g1[reg], TWOS2F, a2i), rm[4 + reg], rs[4 + reg]);
                }
            }
#pragma unroll
            for (int off = 1; off < 16; off <<= 1)
#pragma unroll
                for (int c = 0; c < 8; ++c) {
                    float mo = __shfl_xor(rm[c], off, 64);
                    float so = __shfl_xor(rs[c], off, 64);
                    lse_merge2(mo, so, rm[c], rs[c]);
                }
            if (li == 0) {
#pragma unroll
                for (int c = 0; c < 8; ++c)
                    wavepart[wid][((c >> 2) << 4) + (lg << 2) + (c & 3)] =
                        make_float2(rm[c], rs[c]);
            }
        }
        __syncthreads();
        if (tid < 32) {
            float m = wavepart[0][tid].x, s = wavepart[0][tid].y;
#pragma unroll
            for (int w = 1; w < 8; ++w)
                lse_merge2(wavepart[w][tid].x, wavepart[w][tid].y, m, s);
            float vnew = eps_logmu + ynr - EPSLN2 * (m + LOG2F(s));
            int gj = b * P + r0 + tid;
            vg[gj] = vnew;                        // read by final kernel only
            st_coh(&w2g[gj], (vnew - ynr) * S2F); // cross-block (coherent)
        }
        unsigned g = gridbar(flags, gen, 2 * t + 2, &errAcc[t]);
        if (g & DONEBIT) break;       // uniform: all blocks see same gen
    }
}

// ---- final: pi = exp((u+v-C)/eps), cost[b] = sum pi*C ---------------------
__global__ __launch_bounds__(256) void final_pi_cost(
        const float* __restrict__ C, const float* __restrict__ u,
        const float* __restrict__ vg, float* __restrict__ pi,
        float* __restrict__ cost) {
    __shared__ float sc[B];
    const int tid = threadIdx.x, lane = tid & 63, wid = tid >> 6;
    if (tid < B) sc[tid] = 0.0f;
    __syncthreads();
    const int gw = blockIdx.x * 4 + wid;      // 0..4095
    const int rbase = gw * 4;
    if (rbase >= B * P) return;               // defensive
    const int b = rbase >> 11;
    const float4* vrow = (const float4*)(vg + b * P);
    float acc = 0.0f;
    for (int k = 0; k < 4; ++k) {
        const int r = rbase + k;
        const float ur = u[r];
        const float4* Crow = (const float4*)(C + (size_t)r * P);
        float4* prow = (float4*)(pi + (size_t)r * P);
        for (int it = lane; it < P / 4; it += 64) {
            float4 c4 = Crow[it];
            float4 v4 = vrow[it];
            float4 p4;
            p4.x = __expf((ur + v4.x - c4.x) * INVEPS);
            p4.y = __expf((ur + v4.y - c4.y) * INVEPS);
            p4.z = __expf((ur + v4.z - c4.z) * INVEPS);
            p4.w = __expf((ur + v4.w - c4.w) * INVEPS);
            prow[it] = p4;
            acc += p4.x * c4.x + p4.y * c4.y + p4.z * c4.z + p4.w * c4.w;
        }
    }
#pragma unroll
    for (int off = 32; off; off >>= 1) acc += __shfl_xor(acc, off, 64);
    if (lane == 0) atomicAdd(&sc[b], acc);
    __syncthreads();
    if (tid < B && sc[tid] != 0.0f) atomicAdd(&cost[tid], sc[tid]);
}

extern "C" void kernel_launch(void* const* d_in, const int* in_sizes, int n_in,
                              void* d_out, int out_size, void* d_ws, size_t ws_size,
                              hipStream_t stream) {
    const float* x = (const float*)d_in[0];
    const float* y = (const float*)d_in[1];
    float* out  = (float*)d_out;
    float* cost = out;                              // [8]
    float* pi   = out + 8;                          // [8*2048*2048]
    float* C    = out + 8 + (size_t)B * P * P;      // [8*2048*2048]

    // Scratch lives in the pi output region (dead until final_pi_cost
    // overwrites the whole region):
    _Float16* xh  = (_Float16*)pi;                  // 2 MB (524288 floats)
    _Float16* yh  = (_Float16*)(pi + 524288);       // 2 MB
    float*    xnb = pi + 1048576;                   // B*P
    float*    ynb = xnb + B * P;
    float*    w2g = ynb + B * P;
    float*    a2g = w2g + B * P;

    float* ws       = (float*)d_ws;
    float* u        = ws;                           // B*P
    float* v        = ws + B * P;                   // B*P
    float* errAcc   = ws + 2 * B * P;               // MAXIT
    unsigned* gen   = (unsigned*)(ws + 2 * B * P + 128);   // [1]
    unsigned* flags = gen + 64;                     // NBLK words (2 KB)

    hipLaunchKernelGGL(build_C, dim3(8 * 32 * 32), dim3(256), 0, stream, x, y, C);
    hipLaunchKernelGGL(setup_half, dim3(B * P / 32), dim3(256), 0, stream,
                       x, y, xh, yh, xnb, ynb, w2g);
    hipLaunchKernelGGL(init_ws, dim3(64), dim3(256), 0, stream,
                       u, v, errAcc, gen, flags, cost);

    hipLaunchKernelGGL(iter_persist, dim3(NBLK), dim3(512), 0, stream,
                       (const _Float16*)xh, (const _Float16*)yh,
                       (const float*)xnb, (const float*)ynb,
                       a2g, w2g, u, v, errAcc, flags, gen);

    hipLaunchKernelGGL(final_pi_cost, dim3(1024), dim3(256), 0, stream,
                       (const float*)C, (const float*)u, (const float*)v,
                       pi, cost);
}